// Round 1
// baseline (43.489 us; speedup 1.0000x reference)
//
#include <hip/hip_runtime.h>
#include <math.h>

#define D 512
#define NREL 512
#define NB 1024

// ---- block-wide sum over 256 threads (4 waves of 64) -----------------------
__device__ __forceinline__ float block_reduce_256(float v, float* sbuf) {
#pragma unroll
    for (int off = 32; off > 0; off >>= 1)
        v += __shfl_down(v, off, 64);
    const int lane = threadIdx.x & 63;
    const int wid  = threadIdx.x >> 6;
    __syncthreads();                 // protect sbuf reuse from previous call
    if (lane == 0) sbuf[wid] = v;
    __syncthreads();
    return sbuf[0] + sbuf[1] + sbuf[2] + sbuf[3];
}

// ---- kernel 1: rel_hyp = exp_map_zero(rel_embedding, c); y2 = ||rel_hyp||^2
__global__ __launch_bounds__(256) void relhyp_kernel(
        const float* __restrict__ rel, float* __restrict__ relhyp,
        float* __restrict__ y2) {
    __shared__ float sbuf[4];
    const int r = blockIdx.x;
    const int t = threadIdx.x;              // 0..255, handles elems 2t, 2t+1
    const float sc = 0.1f;                  // sqrt(c), c = 0.01
    const float2 u = *(const float2*)(rel + (size_t)r * D + 2 * t);
    const float uu = block_reduce_256(u.x * u.x + u.y * u.y, sbuf);
    const float n  = fmaxf(sqrtf(uu), 1e-15f);
    const float es = tanhf(sc * n) / (sc * n);
    const float h1 = es * u.x, h2 = es * u.y;
    const float hh = block_reduce_256(h1 * h1 + h2 * h2, sbuf);
    float* dst = relhyp + (size_t)r * D + 2 * t;
    dst[0] = h1; dst[1] = h2;
    if (t == 0) y2[r] = hh;
}

// ---- kernel 2: per-triplet query row + x2 = ||query||^2 --------------------
__global__ __launch_bounds__(256) void query_kernel(
        const float* __restrict__ ent, const int* __restrict__ trip,
        const float* __restrict__ grot, float* __restrict__ query,
        float* __restrict__ x2out) {
    __shared__ float sbuf[4];
    const int b = blockIdx.x;
    const int t = threadIdx.x;              // handles dim pair (2t, 2t+1)
    const float c = 0.01f, sc = 0.1f;

    const int sidx = trip[b * 3 + 0];
    const int oidx = trip[b * 3 + 2];
    const float2 s = *(const float2*)(ent + (size_t)sidx * D + 2 * t);
    const float2 o = *(const float2*)(ent + (size_t)oidx * D + 2 * t);

    // log_map_zero(s)
    const float ss  = block_reduce_256(s.x * s.x + s.y * s.y, sbuf);
    const float n_s = fmaxf(sqrtf(ss), 1e-15f);
    const float arg = fminf(fmaxf(sc * n_s, -1.0f + 1e-7f), 1.0f - 1e-7f);
    const float ls  = atanhf(arg) / (sc * n_s);
    const float x1  = ls * s.x, x2e = ls * s.y;

    // givens rotation (pair 2t,2t+1 uses angle[t])
    float sa, ca;
    sincosf(grot[t], &sa, &ca);
    const float u1 = ca * x1 - sa * x2e;
    const float u2 = sa * x1 + ca * x2e;

    // exp_map_zero(rotated)
    const float uu  = block_reduce_256(u1 * u1 + u2 * u2, sbuf);
    const float n_u = fmaxf(sqrtf(uu), 1e-15f);
    const float es  = tanhf(sc * n_u) / (sc * n_u);
    const float r1  = es * u1, r2 = es * u2;

    // mobius_add(-rot_s, o)
    const float rr = block_reduce_256(r1 * r1 + r2 * r2, sbuf);
    const float oo = block_reduce_256(o.x * o.x + o.y * o.y, sbuf);
    const float ro = block_reduce_256(r1 * o.x + r2 * o.y, sbuf);
    const float xy  = -ro;
    const float A1  = 1.0f + 2.0f * c * xy + c * oo;
    const float B1  = 1.0f - c * rr;
    const float den = fmaxf(1.0f + 2.0f * c * xy + c * c * rr * oo, 1e-15f);
    const float q1  = (A1 * (-r1) + B1 * o.x) / den;
    const float q2  = (A1 * (-r2) + B1 * o.y) / den;

    const float qq = block_reduce_256(q1 * q1 + q2 * q2, sbuf);
    float* dst = query + (size_t)b * D + 2 * t;
    dst[0] = q1; dst[1] = q2;
    if (t == 0) x2out[b] = qq;
}

// ---- kernel 3: 64x64-tile NT GEMM (qd = query . rel_hyp^T) + epilogue ------
__global__ __launch_bounds__(256) void score_kernel(
        const float* __restrict__ query, const float* __restrict__ relhyp,
        const float* __restrict__ x2, const float* __restrict__ y2,
        const float* __restrict__ bias, float* __restrict__ out) {
    __shared__ float As[16][68];   // [k][m], padded to dodge bank conflicts
    __shared__ float Bs[16][68];   // [k][n]
    const int t  = threadIdx.x;
    const int tx = t & 15, ty = t >> 4;
    const int m0 = blockIdx.y * 64;
    const int n0 = blockIdx.x * 64;
    const int loadRow = t >> 2;          // 0..63
    const int loadCol = (t & 3) * 4;     // 0,4,8,12

    float acc[4][4] = {};
    for (int k0 = 0; k0 < D; k0 += 16) {
        const float4 qa = *(const float4*)(query  + (size_t)(m0 + loadRow) * D + k0 + loadCol);
        const float4 qb = *(const float4*)(relhyp + (size_t)(n0 + loadRow) * D + k0 + loadCol);
        __syncthreads();                 // previous iter's reads done
        As[loadCol + 0][loadRow] = qa.x; As[loadCol + 1][loadRow] = qa.y;
        As[loadCol + 2][loadRow] = qa.z; As[loadCol + 3][loadRow] = qa.w;
        Bs[loadCol + 0][loadRow] = qb.x; Bs[loadCol + 1][loadRow] = qb.y;
        Bs[loadCol + 2][loadRow] = qb.z; Bs[loadCol + 3][loadRow] = qb.w;
        __syncthreads();
#pragma unroll
        for (int k = 0; k < 16; ++k) {
            float a[4], b[4];
#pragma unroll
            for (int i = 0; i < 4; ++i) a[i] = As[k][ty * 4 + i];
#pragma unroll
            for (int j = 0; j < 4; ++j) b[j] = Bs[k][tx * 4 + j];
#pragma unroll
            for (int i = 0; i < 4; ++i)
#pragma unroll
                for (int j = 0; j < 4; ++j)
                    acc[i][j] = fmaf(a[i], b[j], acc[i][j]);
        }
    }

    const float c = 0.01f;
#pragma unroll
    for (int i = 0; i < 4; ++i) {
        const int m = m0 + ty * 4 + i;
        const float X2 = x2[m];
        const float B1 = 1.0f - c * X2;
        float res[4];
#pragma unroll
        for (int j = 0; j < 4; ++j) {
            const int n  = n0 + tx * 4 + j;
            const float Y2  = y2[n];
            const float qd  = acc[i][j];
            const float A1  = 1.0f - 2.0f * c * qd + c * Y2;
            const float den = fmaxf(1.0f - 2.0f * c * qd + c * c * X2 * Y2, 1e-15f);
            const float num2 = A1 * A1 * X2 - 2.0f * A1 * B1 * qd + B1 * B1 * Y2;
            res[j] = -(num2 / (den * den)) + bias[n];
        }
        *(float4*)(out + (size_t)m * NREL + n0 + tx * 4) =
            make_float4(res[0], res[1], res[2], res[3]);
    }
}

extern "C" void kernel_launch(void* const* d_in, const int* in_sizes, int n_in,
                              void* d_out, int out_size, void* d_ws, size_t ws_size,
                              hipStream_t stream) {
    const float* ent  = (const float*)d_in[0];   // (20000, 512)
    const float* rel  = (const float*)d_in[1];   // (512, 512)
    const int*   trip = (const int*)d_in[2];     // (1024, 3)
    const float* grot = (const float*)d_in[3];   // (256,)
    const float* bias = (const float*)d_in[4];   // (512,)
    float* out = (float*)d_out;                  // (1024, 512)

    float* ws     = (float*)d_ws;
    float* relhyp = ws;                          // 512*512
    float* y2     = relhyp + (size_t)NREL * D;   // 512
    float* x2     = y2 + NREL;                   // 1024
    float* query  = x2 + NB;                     // 1024*512

    relhyp_kernel<<<dim3(NREL), dim3(256), 0, stream>>>(rel, relhyp, y2);
    query_kernel<<<dim3(NB),   dim3(256), 0, stream>>>(ent, trip, grot, query, x2);
    score_kernel<<<dim3(NREL / 64, NB / 64), dim3(256), 0, stream>>>(
        query, relhyp, x2, y2, bias, out);
}